// Round 1
// baseline (93.579 us; speedup 1.0000x reference)
//
#include <hip/hip_runtime.h>

// SudokuUniqueHVBox (type='h'): per (b,h) unit over [C=9][W=9] bits:
//   s[c] = sum_w m[c][w];  uniq[c] = (s[c]==1)
//   covered[w] = OR_c (uniq[c] & m[c][w])
//   out[c][w]  = m[c][w] & (uniq[c] | !covered[w])
// Inputs are exactly 0.0/1.0 so bit-domain == float reference exactly.

#define BPB 16            // batches per block
#define FPB (BPB * 729)   // floats per block = 11664
#define F4PB (FPB / 4)    // float4 per block = 2916 (16*729*4 bytes = 2916*16, 16B aligned)

__global__ __launch_bounds__(256) void sudoku_hbox_kernel(
    const float* __restrict__ in, float* __restrict__ out, int B) {
    __shared__ float4 lds4[F4PB];
    float* lds = (float*)lds4;

    const int tid = threadIdx.x;
    const long long base = (long long)blockIdx.x * FPB;
    const int b0 = blockIdx.x * BPB;
    const int nb = min(BPB, B - b0);           // batches this block
    const int floats = nb * 729;
    const int nf4 = floats >> 2;               // full float4s
    const int rem = floats - (nf4 << 2);

    // ---- stage in: coalesced float4 global -> LDS ----
    const float4* gin = (const float4*)(in + base);
    #pragma unroll
    for (int i = 0; i < 12; ++i) {
        int idx = tid + i * 256;
        if (idx < nf4) lds4[idx] = gin[idx];
    }
    if (tid < rem) lds[nf4 * 4 + tid] = in[base + nf4 * 4 + tid];
    __syncthreads();

    // ---- compute in place: thread t owns (b_local, h), t < nb*9 ----
    if (tid < nb * 9) {
        const int bl = tid / 9;
        const int h  = tid - bl * 9;
        float* p = lds + bl * 729 + h * 9;     // + c*81 + w

        unsigned rows[9];
        unsigned uniqm = 0;
        #pragma unroll
        for (int c = 0; c < 9; ++c) {
            unsigned bits = 0;
            #pragma unroll
            for (int w = 0; w < 9; ++w)
                bits |= (p[c * 81 + w] > 0.5f) ? (1u << w) : 0u;
            rows[c] = bits;
            if (__popc(bits) == 1) uniqm |= (1u << c);
        }
        unsigned covered = 0;
        #pragma unroll
        for (int c = 0; c < 9; ++c)
            covered |= ((uniqm >> c) & 1u) ? rows[c] : 0u;
        #pragma unroll
        for (int c = 0; c < 9; ++c) {
            unsigned ob = ((uniqm >> c) & 1u) ? rows[c] : (rows[c] & ~covered);
            #pragma unroll
            for (int w = 0; w < 9; ++w)
                p[c * 81 + w] = (float)((ob >> w) & 1u);
        }
    }
    __syncthreads();

    // ---- stage out: LDS -> coalesced float4 global ----
    float4* gout = (float4*)(out + base);
    #pragma unroll
    for (int i = 0; i < 12; ++i) {
        int idx = tid + i * 256;
        if (idx < nf4) gout[idx] = lds4[idx];
    }
    if (tid < rem) out[base + nf4 * 4 + tid] = lds[nf4 * 4 + tid];
}

extern "C" void kernel_launch(void* const* d_in, const int* in_sizes, int n_in,
                              void* d_out, int out_size, void* d_ws, size_t ws_size,
                              hipStream_t stream) {
    const float* in = (const float*)d_in[0];
    float* out = (float*)d_out;
    const int total = in_sizes[0];
    const int B = total / 729;                 // 65536
    const int nblk = (B + BPB - 1) / BPB;      // 4096
    hipLaunchKernelGGL(sudoku_hbox_kernel, dim3(nblk), dim3(256), 0, stream,
                       in, out, B);
}

// Round 3
// 69.205 us; speedup vs baseline: 1.3522x; 1.3522x over previous
//
#include <hip/hip_runtime.h>

// SudokuUniqueHVBox (type='h'): per (b,h) unit over [C=9][W=9] bits:
//   s[c] = sum_w m[c][w];  uniq[c] = (s[c]==1)
//   covered[w] = OR_c (uniq[c] & m[c][w])
//   out[c][w]  = m[c][w] & (uniq[c] | !covered[w])
// Inputs are exactly 0.0/1.0 so bit-domain == float reference exactly.
//
// R3 = R2 with native ext_vector_type(4) float for the nontemporal store
// (HIP's float4 class is rejected by __builtin_nontemporal_store).
// R2 theory: BPB 16 -> 4 (LDS 47KB -> 11.6KB) + launch_bounds(256,8) so
// 8 blocks/CU (32 waves); R1 was occupancy-bound (30%, VGPR=68, 3 blk/CU).

typedef float f4 __attribute__((ext_vector_type(4)));

#define BPB 4             // batches per block
#define FPB (BPB * 729)   // floats per block = 2916
#define F4PB (FPB / 4)    // f4 per block = 729 (2916*4 B = 729*16, 16B aligned)

__global__ __launch_bounds__(256, 8) void sudoku_hbox_kernel(
    const float* __restrict__ in, float* __restrict__ out, int B) {
    __shared__ f4 lds4[F4PB];
    float* lds = (float*)lds4;

    const int tid = threadIdx.x;
    const long long base = (long long)blockIdx.x * FPB;
    const int b0 = blockIdx.x * BPB;
    const int nb = min(BPB, B - b0);           // batches this block
    const int floats = nb * 729;
    const int nf4 = floats >> 2;               // full f4s
    const int rem = floats - (nf4 << 2);

    // ---- stage in: coalesced f4 global -> LDS ----
    const f4* gin = (const f4*)(in + base);
    #pragma unroll
    for (int i = 0; i < 3; ++i) {
        int idx = tid + i * 256;
        if (idx < nf4) lds4[idx] = gin[idx];
    }
    if (tid < rem) lds[nf4 * 4 + tid] = in[base + nf4 * 4 + tid];
    __syncthreads();

    // ---- compute in place: thread t owns (b_local, h), t < nb*9 ----
    if (tid < nb * 9) {
        const int bl = tid / 9;
        const int h  = tid - bl * 9;
        float* p = lds + bl * 729 + h * 9;     // + c*81 + w

        unsigned rows[9];
        unsigned uniqm = 0;
        #pragma unroll
        for (int c = 0; c < 9; ++c) {
            unsigned bits = 0;
            #pragma unroll
            for (int w = 0; w < 9; ++w)
                bits |= (p[c * 81 + w] > 0.5f) ? (1u << w) : 0u;
            rows[c] = bits;
            if (__popc(bits) == 1) uniqm |= (1u << c);
        }
        unsigned covered = 0;
        #pragma unroll
        for (int c = 0; c < 9; ++c)
            covered |= ((uniqm >> c) & 1u) ? rows[c] : 0u;
        #pragma unroll
        for (int c = 0; c < 9; ++c) {
            unsigned ob = ((uniqm >> c) & 1u) ? rows[c] : (rows[c] & ~covered);
            #pragma unroll
            for (int w = 0; w < 9; ++w)
                p[c * 81 + w] = (float)((ob >> w) & 1u);
        }
    }
    __syncthreads();

    // ---- stage out: LDS -> coalesced non-temporal f4 global ----
    f4* gout = (f4*)(out + base);
    #pragma unroll
    for (int i = 0; i < 3; ++i) {
        int idx = tid + i * 256;
        if (idx < nf4) __builtin_nontemporal_store(lds4[idx], &gout[idx]);
    }
    if (tid < rem) __builtin_nontemporal_store(lds[nf4 * 4 + tid], &out[base + nf4 * 4 + tid]);
}

extern "C" void kernel_launch(void* const* d_in, const int* in_sizes, int n_in,
                              void* d_out, int out_size, void* d_ws, size_t ws_size,
                              hipStream_t stream) {
    const float* in = (const float*)d_in[0];
    float* out = (float*)d_out;
    const int total = in_sizes[0];
    const int B = total / 729;                 // 65536
    const int nblk = (B + BPB - 1) / BPB;      // 16384
    hipLaunchKernelGGL(sudoku_hbox_kernel, dim3(nblk), dim3(256), 0, stream,
                       in, out, B);
}

// Round 4
// 61.352 us; speedup vs baseline: 1.5253x; 1.1280x over previous
//
#include <hip/hip_runtime.h>

// SudokuUniqueHVBox (type='h'), bit-domain, LDS holds only 9-bit row masks:
//   rowbits[r] (r = bl*81 + c*9 + h) = 9 bits over w of m[b,c,h,:]
//   unit (bl,h): uniq[c] = popc(row)==1; covered = OR uniq rows;
//   out row = uniq ? row : row & ~covered.  Exact vs float reference (0/1 ints).
//
// R4: replace float LDS staging (1260 LDS-pipe cy/block) with bitmask LDS
// (~450 cy/block): global->reg f4 loads -> ds_or bit assembly -> 36-lane
// register compute -> all-thread expansion -> nt f4 stores. LDS 11.8KB->1.3KB.

typedef float f4 __attribute__((ext_vector_type(4)));

#define BPB 4                 // batches per block
#define FPB (BPB * 729)       // 2916 floats per block
#define NF4 (FPB / 4)         // 729 f4 per block
#define ROWS (BPB * 81)       // 324 row words

__global__ __launch_bounds__(256, 8) void sudoku_hbox_kernel(
    const float* __restrict__ in, float* __restrict__ out, int B) {
    __shared__ unsigned rowbits[ROWS + 8];     // +pad so [r0+1] is always in-bounds

    const int tid = threadIdx.x;
    const long long base = (long long)blockIdx.x * FPB;
    const f4* gin = (const f4*)(in + base);
    f4* gout = (f4*)(out + base);

    // ---- zero row masks ----
    if (tid < ROWS + 8 - 256) rowbits[tid + 256] = 0u;
    rowbits[tid] = 0u;
    __syncthreads();

    // ---- phase 1: global f4 -> 4-bit masks -> ds_or into rowbits ----
    #pragma unroll
    for (int i = 0; i < 3; ++i) {
        int idx = tid + i * 256;
        if (idx < NF4) {
            f4 v = gin[idx];
            int o  = idx * 4;              // float offset in block
            int r0 = o / 9;
            int w0 = o - r0 * 9;
            unsigned m4 = (v.x > 0.5f ? 1u : 0u) | (v.y > 0.5f ? 2u : 0u) |
                          (v.z > 0.5f ? 4u : 0u) | (v.w > 0.5f ? 8u : 0u);
            unsigned or0 = (m4 << w0) & 0x1FFu;
            atomicOr(&rowbits[r0], or0);
            if (w0 > 5) {                  // straddles into next row
                unsigned or1 = m4 >> (9 - w0);
                atomicOr(&rowbits[r0 + 1], or1);
            }
        }
    }
    __syncthreads();

    // ---- phase 2: one lane per (bl, h) unit, in-register solve ----
    if (tid < BPB * 9) {
        const int bl = tid / 9;
        const int h  = tid - bl * 9;
        const int rb = bl * 81 + h;        // + c*9
        unsigned rows[9], uniqm = 0;
        #pragma unroll
        for (int c = 0; c < 9; ++c) {
            rows[c] = rowbits[rb + c * 9];
            if (__popc(rows[c]) == 1) uniqm |= (1u << c);
        }
        unsigned covered = 0;
        #pragma unroll
        for (int c = 0; c < 9; ++c)
            covered |= ((uniqm >> c) & 1u) ? rows[c] : 0u;
        #pragma unroll
        for (int c = 0; c < 9; ++c) {
            unsigned ob = ((uniqm >> c) & 1u) ? rows[c] : (rows[c] & ~covered);
            rowbits[rb + c * 9] = ob;      // in-place: word owned by this lane only
        }
    }
    __syncthreads();

    // ---- phase 3: expand rowbits -> f4, nt store direct to global ----
    #pragma unroll
    for (int i = 0; i < 3; ++i) {
        int idx = tid + i * 256;
        if (idx < NF4) {
            int o  = idx * 4;
            int r0 = o / 9;
            int w0 = o - r0 * 9;
            unsigned v0 = rowbits[r0];
            unsigned v1 = rowbits[r0 + 1];
            unsigned win = (v0 >> w0) | (v1 << (9 - w0));  // w0=0: v1 bits >=9, unused
            f4 ov;
            ov.x = (win & 1u) ? 1.0f : 0.0f;
            ov.y = (win & 2u) ? 1.0f : 0.0f;
            ov.z = (win & 4u) ? 1.0f : 0.0f;
            ov.w = (win & 8u) ? 1.0f : 0.0f;
            __builtin_nontemporal_store(ov, &gout[idx]);
        }
    }
}

extern "C" void kernel_launch(void* const* d_in, const int* in_sizes, int n_in,
                              void* d_out, int out_size, void* d_ws, size_t ws_size,
                              hipStream_t stream) {
    const float* in = (const float*)d_in[0];
    float* out = (float*)d_out;
    const int total = in_sizes[0];
    const int B = total / 729;                 // 65536 (divisible by BPB=4)
    const int nblk = (B + BPB - 1) / BPB;      // 16384
    hipLaunchKernelGGL(sudoku_hbox_kernel, dim3(nblk), dim3(256), 0, stream,
                       in, out, B);
}